// Round 13
// baseline (192.320 us; speedup 1.0000x reference)
//
#include <hip/hip_runtime.h>
#include <hip/hip_bf16.h>

// ---------------------------------------------------------------------------
// GraphSage forward on MI355X — round 13: single-tile-per-block gemm_ZY.
//   prep_weights: Wzy[512,256]=bf16([W1L;W1R]), W2b, W3b        (1 dispatch)
//   gemm_ZY: 3125 blocks, 1 tile each — no loop, no prefetch; overlap comes
//            from resident-block turnover instead of intra-block pipelining.
//   agg_kernel: comb[b,:256] = relu(Z[T0] + mean25 Y8[T1])
//               comb[b,256:] = mean25 relu(Z[T1] + mean10 Y8[T2])
//   embd = relu(comb @ W2^T); out = embd @ W3^T
// ---------------------------------------------------------------------------

typedef __bf16  bf16x8 __attribute__((ext_vector_type(8)));
typedef __bf16  bf16x4 __attribute__((ext_vector_type(4)));
typedef float   f32x4  __attribute__((ext_vector_type(4)));
typedef float   f32x2  __attribute__((ext_vector_type(2)));

#define BATCH     4096
#define F1        25
#define F2        10
#define NNODES    100000
#define ZY_NT     3125          // 100000 / 32 M-tiles

__device__ __forceinline__ uint2 pack4_bf16(float a, float b, float c, float d) {
    union { __bf16 h[4]; uint2 u; } p;
    p.h[0] = (__bf16)a; p.h[1] = (__bf16)b; p.h[2] = (__bf16)c; p.h[3] = (__bf16)d;
    return p.u;
}

__device__ __forceinline__ f32x2 pkmax0(f32x2 v) {
    f32x2 r; r[0] = fmaxf(v[0], 0.f); r[1] = fmaxf(v[1], 0.f); return r;
}

// ---- merged weight prep: Wzy (blocks 0..63), W2b (64..127), W3b (128..135)
__global__ __launch_bounds__(256) void prep_weights(const float* __restrict__ W1,
                                                    const float* __restrict__ W2,
                                                    const float* __restrict__ W3,
                                                    __bf16* __restrict__ Wzy,
                                                    __bf16* __restrict__ W2b,
                                                    __bf16* __restrict__ W3b) {
    int blk = blockIdx.x;
    if (blk < 64) {
        int i = blk * 256 + threadIdx.x;       // 16384 threads, bf16x8 each
        int r  = i >> 5;
        int c0 = (i & 31) * 8;
        const float* src = (r < 256) ? (W1 + (size_t)r * 512 + c0)
                                     : (W1 + (size_t)(r - 256) * 512 + 256 + c0);
        float4 a = reinterpret_cast<const float4*>(src)[0];
        float4 b = reinterpret_cast<const float4*>(src)[1];
        uint4 o;
        uint2 pa = pack4_bf16(a.x, a.y, a.z, a.w);
        uint2 pb = pack4_bf16(b.x, b.y, b.z, b.w);
        o.x = pa.x; o.y = pa.y; o.z = pb.x; o.w = pb.y;
        *reinterpret_cast<uint4*>(Wzy + (size_t)r * 256 + c0) = o;
    } else {
        const float* in; __bf16* out;
        int i;
        if (blk < 128) { in = W2; out = W2b; i = (blk - 64) * 256 + threadIdx.x; }
        else           { in = W3; out = W3b; i = (blk - 128) * 256 + threadIdx.x; }
        float4 v0 = reinterpret_cast<const float4*>(in)[i * 2];
        float4 v1 = reinterpret_cast<const float4*>(in)[i * 2 + 1];
        uint4 o;
        uint2 a = pack4_bf16(v0.x, v0.y, v0.z, v0.w);
        uint2 b = pack4_bf16(v1.x, v1.y, v1.z, v1.w);
        o.x = a.x; o.y = a.y; o.z = b.x; o.w = b.y;
        reinterpret_cast<uint4*>(out)[i] = o;
    }
}

// ---- Ztab/Y8 producer GEMM: M=100000, N=512, K=256 — 1 tile per block -----
// 3125 blocks x 512 threads (8 waves). Wave n-slice: wid 0..3 -> Ztab bf16,
// wid 4..7 -> Y8 fp8. W slice register-resident. A staged fp32->bf16 into a
// single swizzled LDS tile. No loop: block-level turnover provides overlap.
__global__ __launch_bounds__(512, 2) void gemm_ZY(const float* __restrict__ emb,
                                                  const __bf16* __restrict__ Wzy,
                                                  __bf16* __restrict__ Ztab,
                                                  unsigned char* __restrict__ Y8) {
    __shared__ __align__(16) char Abuf[16384];           // [32 rows][512B], swizzled
    __shared__ __align__(16) __bf16 Ybuf[8][32][72];     // epilogue repack tiles
    const int tid  = threadIdx.x;
    const int wid  = tid >> 6;
    const int lane = tid & 63;
    const int lr   = lane & 15;
    const int kg   = lane >> 4;
    const int n0   = wid * 64;
    const int t    = blockIdx.x;
    const int m0   = t * 32;

    // issue A loads first (longest latency): floats [q*2048 + tid*4, +4)
    float4 ld0[4];
    {
        const float4* src = reinterpret_cast<const float4*>(emb + (size_t)t * 8192);
#pragma unroll
        for (int q = 0; q < 4; ++q) ld0[q] = src[q * 512 + tid];
    }

    // W slice (hits L2 after first blocks)
    bf16x8 wfrag[4][8];
    {
        const __bf16* Wb = Wzy + (size_t)(n0 + lr) * 256 + kg * 8;
#pragma unroll
        for (int ni = 0; ni < 4; ++ni)
#pragma unroll
            for (int kt = 0; kt < 8; ++kt)
                wfrag[ni][kt] = *reinterpret_cast<const bf16x8*>(Wb + ni * 16 * 256 + kt * 32);
    }

    // stage A (fp32 -> bf16) into swizzled LDS
#pragma unroll
    for (int q = 0; q < 4; ++q) {
        int e  = q * 2048 + tid * 4;
        int r  = e >> 8;                 // LDS row 0..31
        int cb = (e & 255) * 2;          // byte col
        float4 v = ld0[q];
        *reinterpret_cast<uint2*>(Abuf + r * 512 + (cb ^ ((r & 7) << 4))) =
            pack4_bf16(v.x, v.y, v.z, v.w);
    }
    __syncthreads();

    f32x4 acc[2][4] = {};
#pragma unroll
    for (int kt = 0; kt < 8; ++kt) {
        bf16x8 a[2];
#pragma unroll
        for (int mi = 0; mi < 2; ++mi) {
            int r  = mi * 16 + lr;
            int by = kt * 64 + kg * 16;
            a[mi] = *reinterpret_cast<const bf16x8*>(Abuf + r * 512 + (by ^ ((r & 7) << 4)));
        }
#pragma unroll
        for (int mi = 0; mi < 2; ++mi)
#pragma unroll
            for (int ni = 0; ni < 4; ++ni)
                acc[mi][ni] = __builtin_amdgcn_mfma_f32_16x16x32_bf16(a[mi], wfrag[ni][kt], acc[mi][ni], 0, 0, 0);
    }

    // ---- epilogue: stage wave tile (32x64) in LDS, write coalesced -------
    const int orow = (lane >> 4) * 4;
    const int ocol = lane & 15;
#pragma unroll
    for (int mi = 0; mi < 2; ++mi)
#pragma unroll
        for (int ni = 0; ni < 4; ++ni)
#pragma unroll
            for (int j = 0; j < 4; ++j)
                Ybuf[wid][mi * 16 + orow + j][ni * 16 + ocol] = (__bf16)acc[mi][ni][j];
    // wave-private slice: in-order LDS within the wave, no barrier needed
    const int row = lane & 31;
    const int cg  = (lane >> 5) * 32;
    if (wid < 4) {
#pragma unroll
        for (int q = 0; q < 4; ++q) {
            bf16x8 v = *reinterpret_cast<bf16x8*>(&Ybuf[wid][row][cg + q * 8]);
            *reinterpret_cast<bf16x8*>(Ztab + (size_t)(m0 + row) * 256 + n0 + cg + q * 8) = v;
        }
    } else {
#pragma unroll
        for (int q = 0; q < 4; ++q) {
            bf16x8 v = *reinterpret_cast<bf16x8*>(&Ybuf[wid][row][cg + q * 8]);
            int w0 = 0, w1 = 0;
            w0 = __builtin_amdgcn_cvt_pk_fp8_f32((float)v[0], (float)v[1], w0, false);
            w0 = __builtin_amdgcn_cvt_pk_fp8_f32((float)v[2], (float)v[3], w0, true);
            w1 = __builtin_amdgcn_cvt_pk_fp8_f32((float)v[4], (float)v[5], w1, false);
            w1 = __builtin_amdgcn_cvt_pk_fp8_f32((float)v[6], (float)v[7], w1, true);
            uint2 o; o.x = (unsigned)w0; o.y = (unsigned)w1;
            *reinterpret_cast<uint2*>(Y8 + (size_t)(m0 + row) * 256 + (n0 - 256) + cg + q * 8) = o;
        }
    }
}

// ---- merged aggregation: h0 + h1 (2-stage pipeline, packed f32x2 math) ----
// 1 block (4 waves) per batch. Lane l owns cols [l*4, l*4+4) — fully local.
__global__ __launch_bounds__(256) void agg_kernel(const int* __restrict__ T0,
                                                  const int* __restrict__ T1,
                                                  const int* __restrict__ T2,
                                                  const __bf16* __restrict__ Ztab,
                                                  const unsigned char* __restrict__ Y8,
                                                  __bf16* __restrict__ comb) {
    __shared__ float red1[4][256];
    __shared__ float red0[4][256];
    const int b    = blockIdx.x;
    const int wv   = threadIdx.x >> 6;
    const int lane = threadIdx.x & 63;

    f32x2 m01 = {0.f, 0.f}, m23 = {0.f, 0.f};   // h1 accumulators (4 cols)
    f32x2 g01 = {0.f, 0.f}, g23 = {0.f, 0.f};   // h0 Y-sums

    int f = wv;
    int r0  = __builtin_amdgcn_readfirstlane(b * F1 + f);
    int t1c = T1[r0];
    bf16x4   zc  = *reinterpret_cast<const bf16x4*>(Ztab + (size_t)t1c * 256 + lane * 4);
    unsigned y1c = *reinterpret_cast<const unsigned*>(Y8 + (size_t)t1c * 256 + lane * 4);
    unsigned yvc[F2];
#pragma unroll
    for (int j = 0; j < F2; ++j) {
        int ix = T2[(size_t)r0 * F2 + j];
        yvc[j] = *reinterpret_cast<const unsigned*>(Y8 + (size_t)ix * 256 + lane * 4);
    }

    while (true) {
        const int fn = f + 4;
        const bool more = (fn < F1);
        bf16x4 zn; unsigned y1n; unsigned yvn[F2];
        if (more) {
            int rn  = __builtin_amdgcn_readfirstlane(b * F1 + fn);
            int t1n = T1[rn];
            zn  = *reinterpret_cast<const bf16x4*>(Ztab + (size_t)t1n * 256 + lane * 4);
            y1n = *reinterpret_cast<const unsigned*>(Y8 + (size_t)t1n * 256 + lane * 4);
#pragma unroll
            for (int j = 0; j < F2; ++j) {
                int ix = T2[(size_t)rn * F2 + j];
                yvn[j] = *reinterpret_cast<const unsigned*>(Y8 + (size_t)ix * 256 + lane * 4);
            }
        }
        f32x2 s01 = {0.f, 0.f}, s23 = {0.f, 0.f};
#pragma unroll
        for (int j = 0; j < F2; ++j) {
            s01 += __builtin_amdgcn_cvt_pk_f32_fp8(yvc[j], false);
            s23 += __builtin_amdgcn_cvt_pk_f32_fp8(yvc[j], true);
        }
        g01 += __builtin_amdgcn_cvt_pk_f32_fp8(y1c, false);
        g23 += __builtin_amdgcn_cvt_pk_f32_fp8(y1c, true);
        f32x2 z01; z01[0] = (float)zc[0]; z01[1] = (float)zc[1];
        f32x2 z23; z23[0] = (float)zc[2]; z23[1] = (float)zc[3];
        m01 += pkmax0(z01 + s01 * (1.0f / F2));
        m23 += pkmax0(z23 + s23 * (1.0f / F2));
        if (!more) break;
        f = fn; zc = zn; y1c = y1n;
#pragma unroll
        for (int j = 0; j < F2; ++j) yvc[j] = yvn[j];
    }

    {
        float4 t1v; t1v.x = m01[0]; t1v.y = m01[1]; t1v.z = m23[0]; t1v.w = m23[1];
        float4 t0v; t0v.x = g01[0]; t0v.y = g01[1]; t0v.z = g23[0]; t0v.w = g23[1];
        *reinterpret_cast<float4*>(&red1[wv][lane * 4]) = t1v;
        *reinterpret_cast<float4*>(&red0[wv][lane * 4]) = t0v;
    }
    __syncthreads();

    const int col = threadIdx.x;
    float s1 = red1[0][col] + red1[1][col] + red1[2][col] + red1[3][col];
    float s0 = red0[0][col] + red0[1][col] + red0[2][col] + red0[3][col];
    const int t0 = T0[b];
    float z0 = (float)Ztab[(size_t)t0 * 256 + col];
    comb[(size_t)b * 512 + col]       = (__bf16)fmaxf(z0 + s0 * (1.0f / F1), 0.0f);
    comb[(size_t)b * 512 + 256 + col] = (__bf16)(s1 * (1.0f / F1));
}

// ---- GEMM: C = relu(A @ W^T), A[M,K] bf16, W[N,K] bf16, C bf16 (ldc) ------
__global__ __launch_bounds__(256) void gemm_relu_bf16(const __bf16* __restrict__ A,
                                                      const __bf16* __restrict__ W,
                                                      __bf16* __restrict__ C,
                                                      int K, int ldc) {
    int wid  = threadIdx.x >> 6;
    int lane = threadIdx.x & 63;
    int m0 = blockIdx.x * 128 + (wid >> 1) * 64;
    int n0 = blockIdx.y * 128 + (wid & 1) * 64;
    int lr = lane & 15;
    int kg = lane >> 4;

    f32x4 acc[4][4] = {};
    const __bf16* Abase = A + (size_t)(m0 + lr) * K + kg * 8;
    const __bf16* Wbase = W + (size_t)(n0 + lr) * K + kg * 8;

    for (int kt = 0; kt < K; kt += 32) {
        bf16x8 a[4], b[4];
#pragma unroll
        for (int i = 0; i < 4; ++i)
            a[i] = *reinterpret_cast<const bf16x8*>(Abase + (size_t)i * 16 * K + kt);
#pragma unroll
        for (int i = 0; i < 4; ++i)
            b[i] = *reinterpret_cast<const bf16x8*>(Wbase + (size_t)i * 16 * K + kt);
#pragma unroll
        for (int mi = 0; mi < 4; ++mi)
#pragma unroll
            for (int ni = 0; ni < 4; ++ni)
                acc[mi][ni] = __builtin_amdgcn_mfma_f32_16x16x32_bf16(a[mi], b[ni], acc[mi][ni], 0, 0, 0);
    }

    int orow = (lane >> 4) * 4;
    int ocol = lane & 15;
#pragma unroll
    for (int mi = 0; mi < 4; ++mi)
#pragma unroll
        for (int ni = 0; ni < 4; ++ni)
#pragma unroll
            for (int j = 0; j < 4; ++j) {
                float v = fmaxf(acc[mi][ni][j], 0.0f);
                C[(size_t)(m0 + mi * 16 + orow + j) * ldc + (n0 + ni * 16 + ocol)] = (__bf16)v;
            }
}

// ---- final GEMM: out = embd @ W3^T, M=4096, N=64, K=256, fp32 out ---------
__global__ __launch_bounds__(256) void gemm_out(const __bf16* __restrict__ A,
                                                const __bf16* __restrict__ W,
                                                float* __restrict__ C) {
    const int K = 256;
    int wid  = threadIdx.x >> 6;
    int lane = threadIdx.x & 63;
    int m0 = blockIdx.x * 128 + wid * 32;
    int lr = lane & 15;
    int kg = lane >> 4;

    f32x4 acc[2][4] = {};
    const __bf16* Abase = A + (size_t)(m0 + lr) * K + kg * 8;
    const __bf16* Wbase = W + (size_t)lr * K + kg * 8;

    for (int kt = 0; kt < K; kt += 32) {
        bf16x8 a[2], b[4];
#pragma unroll
        for (int i = 0; i < 2; ++i)
            a[i] = *reinterpret_cast<const bf16x8*>(Abase + (size_t)i * 16 * K + kt);
#pragma unroll
        for (int i = 0; i < 4; ++i)
            b[i] = *reinterpret_cast<const bf16x8*>(Wbase + (size_t)i * 16 * K + kt);
#pragma unroll
        for (int mi = 0; mi < 2; ++mi)
#pragma unroll
            for (int ni = 0; ni < 4; ++ni)
                acc[mi][ni] = __builtin_amdgcn_mfma_f32_16x16x32_bf16(a[mi], b[ni], acc[mi][ni], 0, 0, 0);
    }

    int orow = (lane >> 4) * 4;
    int ocol = lane & 15;
#pragma unroll
    for (int mi = 0; mi < 2; ++mi)
#pragma unroll
        for (int ni = 0; ni < 4; ++ni)
#pragma unroll
            for (int j = 0; j < 4; ++j)
                C[(size_t)(m0 + mi * 16 + orow + j) * 64 + (ni * 16 + ocol)] = acc[mi][ni][j];
}

extern "C" void kernel_launch(void* const* d_in, const int* in_sizes, int n_in,
                              void* d_out, int out_size, void* d_ws, size_t ws_size,
                              hipStream_t stream) {
    const int*   T0  = (const int*)d_in[0];
    const int*   T1  = (const int*)d_in[1];
    const int*   T2  = (const int*)d_in[2];
    const float* emb = (const float*)d_in[3];
    const float* W1  = (const float*)d_in[4];
    const float* W2  = (const float*)d_in[5];
    const float* W3  = (const float*)d_in[6];
    float* out = (float*)d_out;

    char* ws = (char*)d_ws;
    __bf16*        Wzy  = (__bf16*)(ws);                 //   262144
    __bf16*        W2b  = (__bf16*)(ws + 262144);        //   262144
    __bf16*        W3b  = (__bf16*)(ws + 524288);        //    32768
    __bf16*        comb = (__bf16*)(ws + 557056);        //  4194304
    __bf16*        embd = (__bf16*)(ws + 4751360);       //  2097152
    __bf16*        Ztab = (__bf16*)(ws + 6848512);       // 51200000
    unsigned char* Y8   = (unsigned char*)(ws + 58048512); // 25600000 -> ends 83648512

    prep_weights<<<dim3(136), dim3(256), 0, stream>>>(W1, W2, W3, Wzy, W2b, W3b);

    gemm_ZY<<<dim3(ZY_NT), dim3(512), 0, stream>>>(emb, Wzy, Ztab, Y8);

    agg_kernel<<<dim3(BATCH), dim3(256), 0, stream>>>(T0, T1, T2, Ztab, Y8, comb);

    gemm_relu_bf16<<<dim3(BATCH / 128, 2), dim3(256), 0, stream>>>(comb, W2b, embd, 512, 256);
    gemm_out<<<dim3(BATCH / 128), dim3(256), 0, stream>>>(embd, W3b, out);
}

// Round 14
// 138.453 us; speedup vs baseline: 1.3891x; 1.3891x over previous
//
#include <hip/hip_runtime.h>
#include <hip/hip_bf16.h>

// ---------------------------------------------------------------------------
// GraphSage forward on MI355X — round 14: r9 pipeline + fused tail GEMMs.
//   prep_weights: Wzy[512,256]=bf16([W1L;W1R]), W2b, W3b        (1 dispatch)
//   gemm_ZY: Ztab[100000,256] bf16 = emb@W1L^T ; Y8[100000,256] fp8 = emb@W1R^T
//            (r7/r9 proven structure: shared swizzled LDS, 1-deep prefetch)
//   agg_kernel: comb[b,:256] = relu(Z[T0] + mean25 Y8[T1])
//               comb[b,256:] = mean25 relu(Z[T1] + mean10 Y8[T2])
//   fused_tail: per 128-row tile: embd = relu(comb@W2^T) -> LDS ->
//               out = embd @ W3^T   (no embd global round-trip, 1 dispatch)
// ---------------------------------------------------------------------------

typedef __bf16  bf16x8 __attribute__((ext_vector_type(8)));
typedef __bf16  bf16x4 __attribute__((ext_vector_type(4)));
typedef float   f32x4  __attribute__((ext_vector_type(4)));
typedef float   f32x2  __attribute__((ext_vector_type(2)));

#define BATCH     4096
#define F1        25
#define F2        10
#define NNODES    100000
#define ZY_NT     3125          // 100000 / 32 M-tiles
#define ZY_BLOCKS 512

__device__ __forceinline__ uint2 pack4_bf16(float a, float b, float c, float d) {
    union { __bf16 h[4]; uint2 u; } p;
    p.h[0] = (__bf16)a; p.h[1] = (__bf16)b; p.h[2] = (__bf16)c; p.h[3] = (__bf16)d;
    return p.u;
}

__device__ __forceinline__ f32x2 pkmax0(f32x2 v) {
    f32x2 r; r[0] = fmaxf(v[0], 0.f); r[1] = fmaxf(v[1], 0.f); return r;
}

// ---- merged weight prep: Wzy (blocks 0..63), W2b (64..127), W3b (128..135)
__global__ __launch_bounds__(256) void prep_weights(const float* __restrict__ W1,
                                                    const float* __restrict__ W2,
                                                    const float* __restrict__ W3,
                                                    __bf16* __restrict__ Wzy,
                                                    __bf16* __restrict__ W2b,
                                                    __bf16* __restrict__ W3b) {
    int blk = blockIdx.x;
    if (blk < 64) {
        int i = blk * 256 + threadIdx.x;       // 16384 threads, bf16x8 each
        int r  = i >> 5;
        int c0 = (i & 31) * 8;
        const float* src = (r < 256) ? (W1 + (size_t)r * 512 + c0)
                                     : (W1 + (size_t)(r - 256) * 512 + 256 + c0);
        float4 a = reinterpret_cast<const float4*>(src)[0];
        float4 b = reinterpret_cast<const float4*>(src)[1];
        uint4 o;
        uint2 pa = pack4_bf16(a.x, a.y, a.z, a.w);
        uint2 pb = pack4_bf16(b.x, b.y, b.z, b.w);
        o.x = pa.x; o.y = pa.y; o.z = pb.x; o.w = pb.y;
        *reinterpret_cast<uint4*>(Wzy + (size_t)r * 256 + c0) = o;
    } else {
        const float* in; __bf16* out;
        int i;
        if (blk < 128) { in = W2; out = W2b; i = (blk - 64) * 256 + threadIdx.x; }
        else           { in = W3; out = W3b; i = (blk - 128) * 256 + threadIdx.x; }
        float4 v0 = reinterpret_cast<const float4*>(in)[i * 2];
        float4 v1 = reinterpret_cast<const float4*>(in)[i * 2 + 1];
        uint4 o;
        uint2 a = pack4_bf16(v0.x, v0.y, v0.z, v0.w);
        uint2 b = pack4_bf16(v1.x, v1.y, v1.z, v1.w);
        o.x = a.x; o.y = a.y; o.z = b.x; o.w = b.y;
        reinterpret_cast<uint4*>(out)[i] = o;
    }
}

// ---- Ztab/Y8 producer GEMM: M=100000, N=512, K=256 (r7/r9 proven) ---------
__global__ __launch_bounds__(512, 2) void gemm_ZY(const float* __restrict__ emb,
                                                  const __bf16* __restrict__ Wzy,
                                                  __bf16* __restrict__ Ztab,
                                                  unsigned char* __restrict__ Y8) {
    __shared__ __align__(16) char Abuf[2][16384];        // [32 rows][512B], swizzled
    __shared__ __align__(16) __bf16 Ybuf[8][32][72];     // epilogue repack tiles
    const int tid  = threadIdx.x;
    const int wid  = tid >> 6;
    const int lane = tid & 63;
    const int lr   = lane & 15;
    const int kg   = lane >> 4;
    const int n0   = wid * 64;

    bf16x8 wfrag[4][8];
    {
        const __bf16* Wb = Wzy + (size_t)(n0 + lr) * 256 + kg * 8;
#pragma unroll
        for (int ni = 0; ni < 4; ++ni)
#pragma unroll
            for (int kt = 0; kt < 8; ++kt)
                wfrag[ni][kt] = *reinterpret_cast<const bf16x8*>(Wb + ni * 16 * 256 + kt * 32);
    }

    int soff[4];
#pragma unroll
    for (int q = 0; q < 4; ++q) {
        int e  = q * 2048 + tid * 4;
        int r  = e >> 8;                 // LDS row 0..31
        int cb = (e & 255) * 2;          // byte col
        soff[q] = r * 512 + (cb ^ ((r & 7) << 4));
    }

    int t = blockIdx.x;
    float4 ld0[4];
    {
        const float4* src = reinterpret_cast<const float4*>(emb + (size_t)t * 8192);
#pragma unroll
        for (int q = 0; q < 4; ++q) ld0[q] = src[q * 512 + tid];
    }
    int cur = 0;

    for (; t < ZY_NT; t += ZY_BLOCKS) {
#pragma unroll
        for (int q = 0; q < 4; ++q) {
            float4 v = ld0[q];
            *reinterpret_cast<uint2*>(Abuf[cur] + soff[q]) = pack4_bf16(v.x, v.y, v.z, v.w);
        }
        int tn = t + ZY_BLOCKS;
        float4 ld1[4] = {};
        if (tn < ZY_NT) {
            const float4* src = reinterpret_cast<const float4*>(emb + (size_t)tn * 8192);
#pragma unroll
            for (int q = 0; q < 4; ++q) ld1[q] = src[q * 512 + tid];
        }
        __syncthreads();

        f32x4 acc[2][4] = {};
        const char* Ab = Abuf[cur];
#pragma unroll
        for (int kt = 0; kt < 8; ++kt) {
            bf16x8 a[2];
#pragma unroll
            for (int mi = 0; mi < 2; ++mi) {
                int r  = mi * 16 + lr;
                int by = kt * 64 + kg * 16;
                a[mi] = *reinterpret_cast<const bf16x8*>(Ab + r * 512 + (by ^ ((r & 7) << 4)));
            }
#pragma unroll
            for (int mi = 0; mi < 2; ++mi)
#pragma unroll
                for (int ni = 0; ni < 4; ++ni)
                    acc[mi][ni] = __builtin_amdgcn_mfma_f32_16x16x32_bf16(a[mi], wfrag[ni][kt], acc[mi][ni], 0, 0, 0);
        }

        const int orow = (lane >> 4) * 4;
        const int ocol = lane & 15;
        const int m0   = t * 32;
#pragma unroll
        for (int mi = 0; mi < 2; ++mi)
#pragma unroll
            for (int ni = 0; ni < 4; ++ni)
#pragma unroll
                for (int j = 0; j < 4; ++j)
                    Ybuf[wid][mi * 16 + orow + j][ni * 16 + ocol] = (__bf16)acc[mi][ni][j];
        const int row = lane & 31;
        const int cg  = (lane >> 5) * 32;
        if (wid < 4) {
#pragma unroll
            for (int q = 0; q < 4; ++q) {
                bf16x8 v = *reinterpret_cast<bf16x8*>(&Ybuf[wid][row][cg + q * 8]);
                *reinterpret_cast<bf16x8*>(Ztab + (size_t)(m0 + row) * 256 + n0 + cg + q * 8) = v;
            }
        } else {
#pragma unroll
            for (int q = 0; q < 4; ++q) {
                bf16x8 v = *reinterpret_cast<bf16x8*>(&Ybuf[wid][row][cg + q * 8]);
                int w0 = 0, w1 = 0;
                w0 = __builtin_amdgcn_cvt_pk_fp8_f32((float)v[0], (float)v[1], w0, false);
                w0 = __builtin_amdgcn_cvt_pk_fp8_f32((float)v[2], (float)v[3], w0, true);
                w1 = __builtin_amdgcn_cvt_pk_fp8_f32((float)v[4], (float)v[5], w1, false);
                w1 = __builtin_amdgcn_cvt_pk_fp8_f32((float)v[6], (float)v[7], w1, true);
                uint2 o; o.x = (unsigned)w0; o.y = (unsigned)w1;
                *reinterpret_cast<uint2*>(Y8 + (size_t)(m0 + row) * 256 + (n0 - 256) + cg + q * 8) = o;
            }
        }

#pragma unroll
        for (int q = 0; q < 4; ++q) ld0[q] = ld1[q];
        cur ^= 1;
    }
}

// ---- merged aggregation: h0 + h1 (2-stage pipeline, packed f32x2 math) ----
__global__ __launch_bounds__(256) void agg_kernel(const int* __restrict__ T0,
                                                  const int* __restrict__ T1,
                                                  const int* __restrict__ T2,
                                                  const __bf16* __restrict__ Ztab,
                                                  const unsigned char* __restrict__ Y8,
                                                  __bf16* __restrict__ comb) {
    __shared__ float red1[4][256];
    __shared__ float red0[4][256];
    const int b    = blockIdx.x;
    const int wv   = threadIdx.x >> 6;
    const int lane = threadIdx.x & 63;

    f32x2 m01 = {0.f, 0.f}, m23 = {0.f, 0.f};
    f32x2 g01 = {0.f, 0.f}, g23 = {0.f, 0.f};

    int f = wv;
    int r0  = __builtin_amdgcn_readfirstlane(b * F1 + f);
    int t1c = T1[r0];
    bf16x4   zc  = *reinterpret_cast<const bf16x4*>(Ztab + (size_t)t1c * 256 + lane * 4);
    unsigned y1c = *reinterpret_cast<const unsigned*>(Y8 + (size_t)t1c * 256 + lane * 4);
    unsigned yvc[F2];
#pragma unroll
    for (int j = 0; j < F2; ++j) {
        int ix = T2[(size_t)r0 * F2 + j];
        yvc[j] = *reinterpret_cast<const unsigned*>(Y8 + (size_t)ix * 256 + lane * 4);
    }

    while (true) {
        const int fn = f + 4;
        const bool more = (fn < F1);
        bf16x4 zn; unsigned y1n; unsigned yvn[F2];
        if (more) {
            int rn  = __builtin_amdgcn_readfirstlane(b * F1 + fn);
            int t1n = T1[rn];
            zn  = *reinterpret_cast<const bf16x4*>(Ztab + (size_t)t1n * 256 + lane * 4);
            y1n = *reinterpret_cast<const unsigned*>(Y8 + (size_t)t1n * 256 + lane * 4);
#pragma unroll
            for (int j = 0; j < F2; ++j) {
                int ix = T2[(size_t)rn * F2 + j];
                yvn[j] = *reinterpret_cast<const unsigned*>(Y8 + (size_t)ix * 256 + lane * 4);
            }
        }
        f32x2 s01 = {0.f, 0.f}, s23 = {0.f, 0.f};
#pragma unroll
        for (int j = 0; j < F2; ++j) {
            s01 += __builtin_amdgcn_cvt_pk_f32_fp8(yvc[j], false);
            s23 += __builtin_amdgcn_cvt_pk_f32_fp8(yvc[j], true);
        }
        g01 += __builtin_amdgcn_cvt_pk_f32_fp8(y1c, false);
        g23 += __builtin_amdgcn_cvt_pk_f32_fp8(y1c, true);
        f32x2 z01; z01[0] = (float)zc[0]; z01[1] = (float)zc[1];
        f32x2 z23; z23[0] = (float)zc[2]; z23[1] = (float)zc[3];
        m01 += pkmax0(z01 + s01 * (1.0f / F2));
        m23 += pkmax0(z23 + s23 * (1.0f / F2));
        if (!more) break;
        f = fn; zc = zn; y1c = y1n;
#pragma unroll
        for (int j = 0; j < F2; ++j) yvc[j] = yvn[j];
    }

    {
        float4 t1v; t1v.x = m01[0]; t1v.y = m01[1]; t1v.z = m23[0]; t1v.w = m23[1];
        float4 t0v; t0v.x = g01[0]; t0v.y = g01[1]; t0v.z = g23[0]; t0v.w = g23[1];
        *reinterpret_cast<float4*>(&red1[wv][lane * 4]) = t1v;
        *reinterpret_cast<float4*>(&red0[wv][lane * 4]) = t0v;
    }
    __syncthreads();

    const int col = threadIdx.x;
    float s1 = red1[0][col] + red1[1][col] + red1[2][col] + red1[3][col];
    float s0 = red0[0][col] + red0[1][col] + red0[2][col] + red0[3][col];
    const int t0 = T0[b];
    float z0 = (float)Ztab[(size_t)t0 * 256 + col];
    comb[(size_t)b * 512 + col]       = (__bf16)fmaxf(z0 + s0 * (1.0f / F1), 0.0f);
    comb[(size_t)b * 512 + 256 + col] = (__bf16)(s1 * (1.0f / F1));
}

// ---- fused tail: embd = relu(comb @ W2^T) -> LDS -> out = embd @ W3^T -----
// grid = BATCH/128 = 32 blocks x 256 threads (4 waves).
// Phase 1: wave w computes 64x128 tile (m-half w>>1, n-half w&1), K=512.
// Phase 2: wave w computes rows [w*32, w*32+32) x 64 cols from LDS, K=256.
__global__ __launch_bounds__(256, 1) void fused_tail(const __bf16* __restrict__ comb,
                                                     const __bf16* __restrict__ W2b,
                                                     const __bf16* __restrict__ W3b,
                                                     float* __restrict__ out) {
    __shared__ __bf16 Et[128][264];   // embd tile, +8 pad -> 2-way-only conflicts
    const int wid  = threadIdx.x >> 6;
    const int lane = threadIdx.x & 63;
    const int lr   = lane & 15;
    const int kg   = lane >> 4;
    const int gm0  = blockIdx.x * 128;

    // ---- phase 1: 64x128 per wave, K=512 ----
    {
        const int m0l = (wid >> 1) * 64;
        const int n0l = (wid & 1) * 128;
        f32x4 acc[4][8] = {};
        const __bf16* Abase = comb + (size_t)(gm0 + m0l + lr) * 512 + kg * 8;
        const __bf16* Wbase = W2b + (size_t)(n0l + lr) * 512 + kg * 8;
        for (int kt = 0; kt < 512; kt += 32) {
            bf16x8 a[4], b[8];
#pragma unroll
            for (int i = 0; i < 4; ++i)
                a[i] = *reinterpret_cast<const bf16x8*>(Abase + (size_t)i * 16 * 512 + kt);
#pragma unroll
            for (int i = 0; i < 8; ++i)
                b[i] = *reinterpret_cast<const bf16x8*>(Wbase + (size_t)i * 16 * 512 + kt);
#pragma unroll
            for (int mi = 0; mi < 4; ++mi)
#pragma unroll
                for (int ni = 0; ni < 8; ++ni)
                    acc[mi][ni] = __builtin_amdgcn_mfma_f32_16x16x32_bf16(a[mi], b[ni], acc[mi][ni], 0, 0, 0);
        }
        const int orow = (lane >> 4) * 4;
        const int ocol = lane & 15;
#pragma unroll
        for (int mi = 0; mi < 4; ++mi)
#pragma unroll
            for (int ni = 0; ni < 8; ++ni)
#pragma unroll
                for (int j = 0; j < 4; ++j)
                    Et[m0l + mi * 16 + orow + j][n0l + ni * 16 + ocol] =
                        (__bf16)fmaxf(acc[mi][ni][j], 0.0f);
    }
    __syncthreads();

    // ---- phase 2: 32x64 per wave from LDS, K=256 ----
    {
        const int rl0 = wid * 32;
        f32x4 acc[2][4] = {};
        const __bf16* Wbase = W3b + (size_t)lr * 256 + kg * 8;
        for (int kt = 0; kt < 256; kt += 32) {
            bf16x8 a[2], b[4];
#pragma unroll
            for (int i = 0; i < 2; ++i)
                a[i] = *reinterpret_cast<const bf16x8*>(&Et[rl0 + i * 16 + lr][kt + kg * 8]);
#pragma unroll
            for (int i = 0; i < 4; ++i)
                b[i] = *reinterpret_cast<const bf16x8*>(Wbase + (size_t)i * 16 * 256 + kt);
#pragma unroll
            for (int mi = 0; mi < 2; ++mi)
#pragma unroll
                for (int ni = 0; ni < 4; ++ni)
                    acc[mi][ni] = __builtin_amdgcn_mfma_f32_16x16x32_bf16(a[mi], b[ni], acc[mi][ni], 0, 0, 0);
        }
        const int orow = (lane >> 4) * 4;
        const int ocol = lane & 15;
#pragma unroll
        for (int mi = 0; mi < 2; ++mi)
#pragma unroll
            for (int ni = 0; ni < 4; ++ni)
#pragma unroll
                for (int j = 0; j < 4; ++j)
                    out[(size_t)(gm0 + rl0 + mi * 16 + orow + j) * 64 + (ni * 16 + ocol)] =
                        acc[mi][ni][j];
    }
}

extern "C" void kernel_launch(void* const* d_in, const int* in_sizes, int n_in,
                              void* d_out, int out_size, void* d_ws, size_t ws_size,
                              hipStream_t stream) {
    const int*   T0  = (const int*)d_in[0];
    const int*   T1  = (const int*)d_in[1];
    const int*   T2  = (const int*)d_in[2];
    const float* emb = (const float*)d_in[3];
    const float* W1  = (const float*)d_in[4];
    const float* W2  = (const float*)d_in[5];
    const float* W3  = (const float*)d_in[6];
    float* out = (float*)d_out;

    char* ws = (char*)d_ws;
    __bf16*        Wzy  = (__bf16*)(ws);                 //   262144
    __bf16*        W2b  = (__bf16*)(ws + 262144);        //   262144
    __bf16*        W3b  = (__bf16*)(ws + 524288);        //    32768
    __bf16*        comb = (__bf16*)(ws + 557056);        //  4194304
    __bf16*        Ztab = (__bf16*)(ws + 6848512);       // 51200000
    unsigned char* Y8   = (unsigned char*)(ws + 58048512); // 25600000 -> ends 83648512

    prep_weights<<<dim3(136), dim3(256), 0, stream>>>(W1, W2, W3, Wzy, W2b, W3b);

    gemm_ZY<<<dim3(ZY_BLOCKS), dim3(512), 0, stream>>>(emb, Wzy, Ztab, Y8);

    agg_kernel<<<dim3(BATCH), dim3(256), 0, stream>>>(T0, T1, T2, Ztab, Y8, comb);

    fused_tail<<<dim3(BATCH / 128), dim3(256), 0, stream>>>(comb, W2b, W3b, out);
}

// Round 15
// 129.409 us; speedup vs baseline: 1.4861x; 1.0699x over previous
//
#include <hip/hip_runtime.h>
#include <hip/hip_bf16.h>

// ---------------------------------------------------------------------------
// GraphSage forward on MI355X — round 15: revert to r9 (session best, 130.6us).
//   prep_weights: Wzy[512,256]=bf16([W1L;W1R]), W2b, W3b        (1 dispatch)
//   gemm_ZY: Ztab[100000,256] bf16 = emb@W1L^T ; Y8[100000,256] fp8 = emb@W1R^T
//            (shared swizzled LDS A-tile, 1-deep prefetch, 2 blocks/CU)
//   agg_kernel: comb[b,:256] = relu(Z[T0] + mean25 Y8[T1])
//               comb[b,256:] = mean25 relu(Z[T1] + mean10 Y8[T2])
//   embd = relu(comb @ W2^T); out = embd @ W3^T   (split tail — fusion regressed)
// ---------------------------------------------------------------------------

typedef __bf16  bf16x8 __attribute__((ext_vector_type(8)));
typedef __bf16  bf16x4 __attribute__((ext_vector_type(4)));
typedef float   f32x4  __attribute__((ext_vector_type(4)));
typedef float   f32x2  __attribute__((ext_vector_type(2)));

#define BATCH     4096
#define F1        25
#define F2        10
#define NNODES    100000
#define ZY_NT     3125          // 100000 / 32 M-tiles
#define ZY_BLOCKS 512

__device__ __forceinline__ uint2 pack4_bf16(float a, float b, float c, float d) {
    union { __bf16 h[4]; uint2 u; } p;
    p.h[0] = (__bf16)a; p.h[1] = (__bf16)b; p.h[2] = (__bf16)c; p.h[3] = (__bf16)d;
    return p.u;
}

__device__ __forceinline__ f32x2 pkmax0(f32x2 v) {
    f32x2 r; r[0] = fmaxf(v[0], 0.f); r[1] = fmaxf(v[1], 0.f); return r;
}

// ---- merged weight prep: Wzy (blocks 0..63), W2b (64..127), W3b (128..135)
__global__ __launch_bounds__(256) void prep_weights(const float* __restrict__ W1,
                                                    const float* __restrict__ W2,
                                                    const float* __restrict__ W3,
                                                    __bf16* __restrict__ Wzy,
                                                    __bf16* __restrict__ W2b,
                                                    __bf16* __restrict__ W3b) {
    int blk = blockIdx.x;
    if (blk < 64) {
        int i = blk * 256 + threadIdx.x;       // 16384 threads, bf16x8 each
        int r  = i >> 5;
        int c0 = (i & 31) * 8;
        const float* src = (r < 256) ? (W1 + (size_t)r * 512 + c0)
                                     : (W1 + (size_t)(r - 256) * 512 + 256 + c0);
        float4 a = reinterpret_cast<const float4*>(src)[0];
        float4 b = reinterpret_cast<const float4*>(src)[1];
        uint4 o;
        uint2 pa = pack4_bf16(a.x, a.y, a.z, a.w);
        uint2 pb = pack4_bf16(b.x, b.y, b.z, b.w);
        o.x = pa.x; o.y = pa.y; o.z = pb.x; o.w = pb.y;
        *reinterpret_cast<uint4*>(Wzy + (size_t)r * 256 + c0) = o;
    } else {
        const float* in; __bf16* out;
        int i;
        if (blk < 128) { in = W2; out = W2b; i = (blk - 64) * 256 + threadIdx.x; }
        else           { in = W3; out = W3b; i = (blk - 128) * 256 + threadIdx.x; }
        float4 v0 = reinterpret_cast<const float4*>(in)[i * 2];
        float4 v1 = reinterpret_cast<const float4*>(in)[i * 2 + 1];
        uint4 o;
        uint2 a = pack4_bf16(v0.x, v0.y, v0.z, v0.w);
        uint2 b = pack4_bf16(v1.x, v1.y, v1.z, v1.w);
        o.x = a.x; o.y = a.y; o.z = b.x; o.w = b.y;
        reinterpret_cast<uint4*>(out)[i] = o;
    }
}

// ---- Ztab/Y8 producer GEMM: M=100000, N=512, K=256 (r7/r9 proven) ---------
// 512 blocks x 512 threads (8 waves, 2 blocks/CU). Wave n-slice: wid 0..3 ->
// Ztab bf16, wid 4..7 -> Y8 fp8. W slice register-resident. A staged
// fp32->bf16 into double-buffered swizzled LDS; 1-deep prefetch,
// wave-contiguous loads. launch_bounds(512,2): VGPR cap 256 (no spill).
__global__ __launch_bounds__(512, 2) void gemm_ZY(const float* __restrict__ emb,
                                                  const __bf16* __restrict__ Wzy,
                                                  __bf16* __restrict__ Ztab,
                                                  unsigned char* __restrict__ Y8) {
    __shared__ __align__(16) char Abuf[2][16384];        // [32 rows][512B], swizzled
    __shared__ __align__(16) __bf16 Ybuf[8][32][72];     // epilogue repack tiles
    const int tid  = threadIdx.x;
    const int wid  = tid >> 6;
    const int lane = tid & 63;
    const int lr   = lane & 15;
    const int kg   = lane >> 4;
    const int n0   = wid * 64;

    bf16x8 wfrag[4][8];
    {
        const __bf16* Wb = Wzy + (size_t)(n0 + lr) * 256 + kg * 8;
#pragma unroll
        for (int ni = 0; ni < 4; ++ni)
#pragma unroll
            for (int kt = 0; kt < 8; ++kt)
                wfrag[ni][kt] = *reinterpret_cast<const bf16x8*>(Wb + ni * 16 * 256 + kt * 32);
    }

    // staging geometry: load q covers floats [q*2048 + tid*4, +4) (wave-contig)
    int soff[4];
#pragma unroll
    for (int q = 0; q < 4; ++q) {
        int e  = q * 2048 + tid * 4;
        int r  = e >> 8;                 // LDS row 0..31
        int cb = (e & 255) * 2;          // byte col
        soff[q] = r * 512 + (cb ^ ((r & 7) << 4));
    }

    int t = blockIdx.x;
    float4 ld0[4];
    {
        const float4* src = reinterpret_cast<const float4*>(emb + (size_t)t * 8192);
#pragma unroll
        for (int q = 0; q < 4; ++q) ld0[q] = src[q * 512 + tid];
    }
    int cur = 0;

    for (; t < ZY_NT; t += ZY_BLOCKS) {
        // stage current tile into Abuf[cur] (fp32 -> bf16), 8B LDS writes
#pragma unroll
        for (int q = 0; q < 4; ++q) {
            float4 v = ld0[q];
            *reinterpret_cast<uint2*>(Abuf[cur] + soff[q]) = pack4_bf16(v.x, v.y, v.z, v.w);
        }
        // issue next tile's loads (in flight during compute)
        int tn = t + ZY_BLOCKS;
        float4 ld1[4] = {};
        if (tn < ZY_NT) {
            const float4* src = reinterpret_cast<const float4*>(emb + (size_t)tn * 8192);
#pragma unroll
            for (int q = 0; q < 4; ++q) ld1[q] = src[q * 512 + tid];
        }
        __syncthreads();

        f32x4 acc[2][4] = {};
        const char* Ab = Abuf[cur];
#pragma unroll
        for (int kt = 0; kt < 8; ++kt) {
            bf16x8 a[2];
#pragma unroll
            for (int mi = 0; mi < 2; ++mi) {
                int r  = mi * 16 + lr;
                int by = kt * 64 + kg * 16;
                a[mi] = *reinterpret_cast<const bf16x8*>(Ab + r * 512 + (by ^ ((r & 7) << 4)));
            }
#pragma unroll
            for (int mi = 0; mi < 2; ++mi)
#pragma unroll
                for (int ni = 0; ni < 4; ++ni)
                    acc[mi][ni] = __builtin_amdgcn_mfma_f32_16x16x32_bf16(a[mi], wfrag[ni][kt], acc[mi][ni], 0, 0, 0);
        }

        // ---- epilogue: stage wave tile (32x64) in LDS, write coalesced ---
        const int orow = (lane >> 4) * 4;
        const int ocol = lane & 15;
        const int m0   = t * 32;
#pragma unroll
        for (int mi = 0; mi < 2; ++mi)
#pragma unroll
            for (int ni = 0; ni < 4; ++ni)
#pragma unroll
                for (int j = 0; j < 4; ++j)
                    Ybuf[wid][mi * 16 + orow + j][ni * 16 + ocol] = (__bf16)acc[mi][ni][j];
        // wave-private slice: in-order LDS within the wave, no barrier needed
        const int row = lane & 31;
        const int cg  = (lane >> 5) * 32;
        if (wid < 4) {
#pragma unroll
            for (int q = 0; q < 4; ++q) {
                bf16x8 v = *reinterpret_cast<bf16x8*>(&Ybuf[wid][row][cg + q * 8]);
                *reinterpret_cast<bf16x8*>(Ztab + (size_t)(m0 + row) * 256 + n0 + cg + q * 8) = v;
            }
        } else {
#pragma unroll
            for (int q = 0; q < 4; ++q) {
                bf16x8 v = *reinterpret_cast<bf16x8*>(&Ybuf[wid][row][cg + q * 8]);
                int w0 = 0, w1 = 0;
                w0 = __builtin_amdgcn_cvt_pk_fp8_f32((float)v[0], (float)v[1], w0, false);
                w0 = __builtin_amdgcn_cvt_pk_fp8_f32((float)v[2], (float)v[3], w0, true);
                w1 = __builtin_amdgcn_cvt_pk_fp8_f32((float)v[4], (float)v[5], w1, false);
                w1 = __builtin_amdgcn_cvt_pk_fp8_f32((float)v[6], (float)v[7], w1, true);
                uint2 o; o.x = (unsigned)w0; o.y = (unsigned)w1;
                *reinterpret_cast<uint2*>(Y8 + (size_t)(m0 + row) * 256 + (n0 - 256) + cg + q * 8) = o;
            }
        }

#pragma unroll
        for (int q = 0; q < 4; ++q) ld0[q] = ld1[q];
        cur ^= 1;
    }
}

// ---- merged aggregation: h0 + h1 (2-stage pipeline, packed f32x2 math) ----
// 1 block (4 waves) per batch. Lane l owns cols [l*4, l*4+4) — fully local.
__global__ __launch_bounds__(256) void agg_kernel(const int* __restrict__ T0,
                                                  const int* __restrict__ T1,
                                                  const int* __restrict__ T2,
                                                  const __bf16* __restrict__ Ztab,
                                                  const unsigned char* __restrict__ Y8,
                                                  __bf16* __restrict__ comb) {
    __shared__ float red1[4][256];
    __shared__ float red0[4][256];
    const int b    = blockIdx.x;
    const int wv   = threadIdx.x >> 6;
    const int lane = threadIdx.x & 63;

    f32x2 m01 = {0.f, 0.f}, m23 = {0.f, 0.f};   // h1 accumulators (4 cols)
    f32x2 g01 = {0.f, 0.f}, g23 = {0.f, 0.f};   // h0 Y-sums

    int f = wv;
    int r0  = __builtin_amdgcn_readfirstlane(b * F1 + f);
    int t1c = T1[r0];
    bf16x4   zc  = *reinterpret_cast<const bf16x4*>(Ztab + (size_t)t1c * 256 + lane * 4);
    unsigned y1c = *reinterpret_cast<const unsigned*>(Y8 + (size_t)t1c * 256 + lane * 4);
    unsigned yvc[F2];
#pragma unroll
    for (int j = 0; j < F2; ++j) {
        int ix = T2[(size_t)r0 * F2 + j];
        yvc[j] = *reinterpret_cast<const unsigned*>(Y8 + (size_t)ix * 256 + lane * 4);
    }

    while (true) {
        const int fn = f + 4;
        const bool more = (fn < F1);
        bf16x4 zn; unsigned y1n; unsigned yvn[F2];
        if (more) {
            int rn  = __builtin_amdgcn_readfirstlane(b * F1 + fn);
            int t1n = T1[rn];
            zn  = *reinterpret_cast<const bf16x4*>(Ztab + (size_t)t1n * 256 + lane * 4);
            y1n = *reinterpret_cast<const unsigned*>(Y8 + (size_t)t1n * 256 + lane * 4);
#pragma unroll
            for (int j = 0; j < F2; ++j) {
                int ix = T2[(size_t)rn * F2 + j];
                yvn[j] = *reinterpret_cast<const unsigned*>(Y8 + (size_t)ix * 256 + lane * 4);
            }
        }
        f32x2 s01 = {0.f, 0.f}, s23 = {0.f, 0.f};
#pragma unroll
        for (int j = 0; j < F2; ++j) {
            s01 += __builtin_amdgcn_cvt_pk_f32_fp8(yvc[j], false);
            s23 += __builtin_amdgcn_cvt_pk_f32_fp8(yvc[j], true);
        }
        g01 += __builtin_amdgcn_cvt_pk_f32_fp8(y1c, false);
        g23 += __builtin_amdgcn_cvt_pk_f32_fp8(y1c, true);
        f32x2 z01; z01[0] = (float)zc[0]; z01[1] = (float)zc[1];
        f32x2 z23; z23[0] = (float)zc[2]; z23[1] = (float)zc[3];
        m01 += pkmax0(z01 + s01 * (1.0f / F2));
        m23 += pkmax0(z23 + s23 * (1.0f / F2));
        if (!more) break;
        f = fn; zc = zn; y1c = y1n;
#pragma unroll
        for (int j = 0; j < F2; ++j) yvc[j] = yvn[j];
    }

    {
        float4 t1v; t1v.x = m01[0]; t1v.y = m01[1]; t1v.z = m23[0]; t1v.w = m23[1];
        float4 t0v; t0v.x = g01[0]; t0v.y = g01[1]; t0v.z = g23[0]; t0v.w = g23[1];
        *reinterpret_cast<float4*>(&red1[wv][lane * 4]) = t1v;
        *reinterpret_cast<float4*>(&red0[wv][lane * 4]) = t0v;
    }
    __syncthreads();

    const int col = threadIdx.x;
    float s1 = red1[0][col] + red1[1][col] + red1[2][col] + red1[3][col];
    float s0 = red0[0][col] + red0[1][col] + red0[2][col] + red0[3][col];
    const int t0 = T0[b];
    float z0 = (float)Ztab[(size_t)t0 * 256 + col];
    comb[(size_t)b * 512 + col]       = (__bf16)fmaxf(z0 + s0 * (1.0f / F1), 0.0f);
    comb[(size_t)b * 512 + 256 + col] = (__bf16)(s1 * (1.0f / F1));
}

// ---- GEMM: C = relu(A @ W^T), A[M,K] bf16, W[N,K] bf16, C bf16 (ldc) ------
__global__ __launch_bounds__(256) void gemm_relu_bf16(const __bf16* __restrict__ A,
                                                      const __bf16* __restrict__ W,
                                                      __bf16* __restrict__ C,
                                                      int K, int ldc) {
    int wid  = threadIdx.x >> 6;
    int lane = threadIdx.x & 63;
    int m0 = blockIdx.x * 128 + (wid >> 1) * 64;
    int n0 = blockIdx.y * 128 + (wid & 1) * 64;
    int lr = lane & 15;
    int kg = lane >> 4;

    f32x4 acc[4][4] = {};
    const __bf16* Abase = A + (size_t)(m0 + lr) * K + kg * 8;
    const __bf16* Wbase = W + (size_t)(n0 + lr) * K + kg * 8;

    for (int kt = 0; kt < K; kt += 32) {
        bf16x8 a[4], b[4];
#pragma unroll
        for (int i = 0; i < 4; ++i)
            a[i] = *reinterpret_cast<const bf16x8*>(Abase + (size_t)i * 16 * K + kt);
#pragma unroll
        for (int i = 0; i < 4; ++i)
            b[i] = *reinterpret_cast<const bf16x8*>(Wbase + (size_t)i * 16 * K + kt);
#pragma unroll
        for (int mi = 0; mi < 4; ++mi)
#pragma unroll
            for (int ni = 0; ni < 4; ++ni)
                acc[mi][ni] = __builtin_amdgcn_mfma_f32_16x16x32_bf16(a[mi], b[ni], acc[mi][ni], 0, 0, 0);
    }

    int orow = (lane >> 4) * 4;
    int ocol = lane & 15;
#pragma unroll
    for (int mi = 0; mi < 4; ++mi)
#pragma unroll
        for (int ni = 0; ni < 4; ++ni)
#pragma unroll
            for (int j = 0; j < 4; ++j) {
                float v = fmaxf(acc[mi][ni][j], 0.0f);
                C[(size_t)(m0 + mi * 16 + orow + j) * ldc + (n0 + ni * 16 + ocol)] = (__bf16)v;
            }
}

// ---- final GEMM: out = embd @ W3^T, M=4096, N=64, K=256, fp32 out ---------
__global__ __launch_bounds__(256) void gemm_out(const __bf16* __restrict__ A,
                                                const __bf16* __restrict__ W,
                                                float* __restrict__ C) {
    const int K = 256;
    int wid  = threadIdx.x >> 6;
    int lane = threadIdx.x & 63;
    int m0 = blockIdx.x * 128 + wid * 32;
    int lr = lane & 15;
    int kg = lane >> 4;

    f32x4 acc[2][4] = {};
    const __bf16* Abase = A + (size_t)(m0 + lr) * K + kg * 8;
    const __bf16* Wbase = W + (size_t)lr * K + kg * 8;

    for (int kt = 0; kt < K; kt += 32) {
        bf16x8 a[2], b[4];
#pragma unroll
        for (int i = 0; i < 2; ++i)
            a[i] = *reinterpret_cast<const bf16x8*>(Abase + (size_t)i * 16 * K + kt);
#pragma unroll
        for (int i = 0; i < 4; ++i)
            b[i] = *reinterpret_cast<const bf16x8*>(Wbase + (size_t)i * 16 * K + kt);
#pragma unroll
        for (int mi = 0; mi < 2; ++mi)
#pragma unroll
            for (int ni = 0; ni < 4; ++ni)
                acc[mi][ni] = __builtin_amdgcn_mfma_f32_16x16x32_bf16(a[mi], b[ni], acc[mi][ni], 0, 0, 0);
    }

    int orow = (lane >> 4) * 4;
    int ocol = lane & 15;
#pragma unroll
    for (int mi = 0; mi < 2; ++mi)
#pragma unroll
        for (int ni = 0; ni < 4; ++ni)
#pragma unroll
            for (int j = 0; j < 4; ++j)
                C[(size_t)(m0 + mi * 16 + orow + j) * 64 + (ni * 16 + ocol)] = acc[mi][ni][j];
}

extern "C" void kernel_launch(void* const* d_in, const int* in_sizes, int n_in,
                              void* d_out, int out_size, void* d_ws, size_t ws_size,
                              hipStream_t stream) {
    const int*   T0  = (const int*)d_in[0];
    const int*   T1  = (const int*)d_in[1];
    const int*   T2  = (const int*)d_in[2];
    const float* emb = (const float*)d_in[3];
    const float* W1  = (const float*)d_in[4];
    const float* W2  = (const float*)d_in[5];
    const float* W3  = (const float*)d_in[6];
    float* out = (float*)d_out;

    char* ws = (char*)d_ws;
    __bf16*        Wzy  = (__bf16*)(ws);                 //   262144
    __bf16*        W2b  = (__bf16*)(ws + 262144);        //   262144
    __bf16*        W3b  = (__bf16*)(ws + 524288);        //    32768
    __bf16*        comb = (__bf16*)(ws + 557056);        //  4194304
    __bf16*        embd = (__bf16*)(ws + 4751360);       //  2097152
    __bf16*        Ztab = (__bf16*)(ws + 6848512);       // 51200000
    unsigned char* Y8   = (unsigned char*)(ws + 58048512); // 25600000 -> ends 83648512

    prep_weights<<<dim3(136), dim3(256), 0, stream>>>(W1, W2, W3, Wzy, W2b, W3b);

    gemm_ZY<<<dim3(ZY_BLOCKS), dim3(512), 0, stream>>>(emb, Wzy, Ztab, Y8);

    agg_kernel<<<dim3(BATCH), dim3(256), 0, stream>>>(T0, T1, T2, Ztab, Y8, comb);

    gemm_relu_bf16<<<dim3(BATCH / 128, 2), dim3(256), 0, stream>>>(comb, W2b, embd, 512, 256);
    gemm_out<<<dim3(BATCH / 128), dim3(256), 0, stream>>>(embd, W3b, out);
}